// Round 12
// baseline (124.279 us; speedup 1.0000x reference)
//
#include <hip/hip_runtime.h>
#include <stdint.h>

#define D_DIM   512
#define BM      128
#define BK      32
#define THREADS 512            // 8 waves; wave tile 128 rows x 64 cols (m=8, nt=4)
#define NBLOCKS 1024           // 131072 / 128

typedef __attribute__((ext_vector_type(8))) __bf16 bf16x8;
typedef __attribute__((ext_vector_type(4))) float  f32x4;

__device__ __forceinline__ unsigned short f32_to_bf16_rne(float f) {
    uint32_t u = __builtin_bit_cast(uint32_t, f);
    u += 0x7FFFu + ((u >> 16) & 1u);
    return (unsigned short)(u >> 16);
}

// Repack L (fp32 row-major [K=512][N=512]) into bf16 fragment order:
// flat ushort idx = ((ks*32 + ntg)*64 + lane)*8 + e  holds L[k][n],
//   n = ntg*16 + (lane&15),  k = ks*32 + (lane>>4)*8 + e.
__global__ void prep_lt(const float* __restrict__ L, unsigned short* __restrict__ Ltf) {
    int o = blockIdx.x * 256 + threadIdx.x;
    #pragma unroll
    for (int i = 0; i < 4; ++i) {
        int idx  = o + i * 65536;
        int e    = idx & 7;
        int l    = (idx >> 3) & 63;
        int tile = idx >> 9;
        int ntg  = tile & 31;
        int ks   = tile >> 5;
        int n    = ntg * 16 + (l & 15);
        int k    = ks * 32 + (l >> 4) * 8 + e;
        Ltf[idx] = f32_to_bf16_rne(L[k * 512 + n]);
    }
}

__global__ __launch_bounds__(THREADS, 2)
void psd_main(const float* __restrict__ x, const unsigned short* __restrict__ Ltf,
              const float* __restrict__ b, const float* __restrict__ c,
              float* __restrict__ out) {
    // 3-slot fp32 ring, slot = [128 rows][32 cols] (16 KiB). Stored 16B-unit u
    // at row r holds logical unit u ^ (r&7) (involution; 8 units per 128B row).
    __shared__ __align__(16) float As[3][BM * BK];   // 48 KiB
    __shared__ __align__(16) float bsh[D_DIM];       // 2 KiB
    __shared__ float wpart[8][BM];                   // 4 KiB
    __shared__ float bpart[BM];

    const int t    = threadIdx.x;
    const int w    = t >> 6;          // wave 0..7; owns n-cols [w*64, w*64+64)
    const int lane = t & 63;
    const int g    = lane >> 4;
    const int ln   = lane & 15;
    const int r8   = lane >> 3;       // stage: row sub-index (0..7)
    const int u8   = lane & 7;        // stage: stored 16B unit

    char* AsB  = (char*)&As[0][0];
    char* bshB = (char*)&bsh[0];
    const char* xB = (const char*)x + (size_t)blockIdx.x * (BM * 2048);

    // fragment-order L base for this wave (ntg = w*4 + nt)
    const unsigned short* LtW = Ltf + (size_t)w * 2048 + (size_t)lane * 8;

    f32x4 acc[8][4];
    #pragma unroll
    for (int m = 0; m < 8; ++m)
        #pragma unroll
        for (int nt = 0; nt < 4; ++nt)
            acc[m][nt] = (f32x4){0.f, 0.f, 0.f, 0.f};
    float bacc = 0.f;

    // Stage K-slice (col byte offset QOFF) into slot SL. Wave w covers rows
    // [w*16, w*16+16); 2 loads/thread; linear LDS dest, pre-swizzled global src.
#define STAGE(QOFF, SL)                                                                  \
    {                                                                                    \
        char* ldsw = AsB + (SL) * 16384 + w * 2048;                                      \
        _Pragma("unroll")                                                                \
        for (int j = 0; j < 2; ++j) {                                                    \
            const int row = w * 16 + j * 8 + r8;                                         \
            const char* gsrc = xB + (size_t)row * 2048 + (QOFF)                          \
                             + ((u8 ^ r8) << 4);                                         \
            __builtin_amdgcn_global_load_lds(                                            \
                (const __attribute__((address_space(1))) void*)gsrc,                     \
                (__attribute__((address_space(3))) void*)(ldsw + j * 1024), 16, 0, 0);   \
        }                                                                                \
    }

    // One K-step (K=32): 8 m-frags from slot RB (fp32->bf16 in regs) x bcur[4].
#define COMPUTE(RB)                                                                      \
    {                                                                                    \
        _Pragma("unroll")                                                                \
        for (int m = 0; m < 8; ++m) {                                                    \
            const int row = m * 16 + ln;                                                 \
            const int cb  = g * 2;                                                       \
            f32x4 f0 = *(const f32x4*)((RB) + row * 128 + (((cb    ) ^ (row & 7)) << 4));\
            f32x4 f1 = *(const f32x4*)((RB) + row * 128 + (((cb + 1) ^ (row & 7)) << 4));\
            bf16x8 a;                                                                    \
            a[0] = (__bf16)f0[0]; a[1] = (__bf16)f0[1];                                  \
            a[2] = (__bf16)f0[2]; a[3] = (__bf16)f0[3];                                  \
            a[4] = (__bf16)f1[0]; a[5] = (__bf16)f1[1];                                  \
            a[6] = (__bf16)f1[2]; a[7] = (__bf16)f1[3];                                  \
            _Pragma("unroll")                                                            \
            for (int nt = 0; nt < 4; ++nt)                                               \
                acc[m][nt] = __builtin_amdgcn_mfma_f32_16x16x32_bf16(a, bcur[nt], acc[m][nt], 0, 0, 0); \
        }                                                                                \
    }

    // x.b partial: thread covers row t>>2, units (t&3)*2 .. +1; b from LDS.
#define XB(RB, BOFF)                                                                     \
    {                                                                                    \
        const int row = t >> 2;                                                          \
        const int rsw = row & 7;                                                         \
        _Pragma("unroll")                                                                \
        for (int i = 0; i < 2; ++i) {                                                    \
            const int unit = (t & 3) * 2 + i;                                            \
            f32x4 xv = *(const f32x4*)((RB) + row * 128 + ((unit ^ rsw) << 4));          \
            f32x4 bv = *(const f32x4*)(bshB + (BOFF) + unit * 16);                       \
            bacc += xv[0] * bv[0] + xv[1] * bv[1] + xv[2] * bv[2] + xv[3] * bv[3];       \
        }                                                                                \
    }

    // ---- prologue: b, slice 0, slice 1 ----
    if (t < 128) {
        const char* gsrc = (const char*)b + (size_t)t * 16;
        __builtin_amdgcn_global_load_lds(
            (const __attribute__((address_space(1))) void*)gsrc,
            (__attribute__((address_space(3))) void*)(bshB + t * 16), 16, 0, 0);
    }
    STAGE(0, 0)
    STAGE(128, 1)
    asm volatile("s_waitcnt vmcnt(2)" ::: "memory");   // b + slice0 landed; slice1 flying
    __builtin_amdgcn_s_barrier();

    // first B-fragment set (slice 0); exposed L2 latency once per block
    bf16x8 bcur[4];
    #pragma unroll
    for (int nt = 0; nt < 4; ++nt)
        bcur[nt] = *(const bf16x8*)(LtW + nt * 512);

    // ---- main loop: steps 0..13 ----
    int sl   = 0;                 // compute slot (= q % 3)
    int qoff = 2 * 128;           // stage byte-col offset (slice q+2)
    int boff = 0;
    const unsigned short* Lp = LtW;

    #pragma unroll 1
    for (int q = 0; q < 14; ++q) {
        // B-fragments for step q+1 FIRST (older than stage in vmcnt order,
        // so their consume-wait next step never drains the stage loads)
        bf16x8 bnxt[4];
        #pragma unroll
        for (int nt = 0; nt < 4; ++nt)
            bnxt[nt] = *(const bf16x8*)(Lp + 16384 + nt * 512);
        __builtin_amdgcn_sched_barrier(0);

        int sls = sl + 2; if (sls >= 3) sls -= 3;
        STAGE(qoff, sls)

        const char* rb = AsB + sl * 16384;
        COMPUTE(rb)
        XB(rb, boff)

        asm volatile("s_waitcnt lgkmcnt(0)" ::: "memory");
        asm volatile("s_waitcnt vmcnt(6)" ::: "memory");  // slice q+1 landed; B(q+1)+S(q+2) fly
        __builtin_amdgcn_s_barrier();

        #pragma unroll
        for (int nt = 0; nt < 4; ++nt) bcur[nt] = bnxt[nt];
        if (++sl == 3) sl = 0;
        qoff += 128;
        boff += 128;
        Lp   += 16384;
    }

    // ---- step 14: compute slot 2; prefetch B(15); wait slice 15 ----
    {
        bf16x8 bnxt[4];
        #pragma unroll
        for (int nt = 0; nt < 4; ++nt)
            bnxt[nt] = *(const bf16x8*)(Lp + 16384 + nt * 512);
        const char* rb = AsB + 2 * 16384;
        COMPUTE(rb)
        XB(rb, 14 * 128)
        asm volatile("s_waitcnt lgkmcnt(0)" ::: "memory");
        asm volatile("s_waitcnt vmcnt(4)" ::: "memory");  // slice 15 landed; B(15) flying
        __builtin_amdgcn_s_barrier();
        #pragma unroll
        for (int nt = 0; nt < 4; ++nt) bcur[nt] = bnxt[nt];
    }
    // ---- step 15: compute slot 0 ----
    {
        const char* rb = AsB;
        COMPUTE(rb)
        XB(rb, 15 * 128)
    }

#undef STAGE
#undef COMPUTE
#undef XB

    // rowsum of squares; C/D layout: col = lane&15, row = 4*(lane>>4) + reg
    #pragma unroll
    for (int m = 0; m < 8; ++m) {
        #pragma unroll
        for (int r = 0; r < 4; ++r) {
            float s = 0.f;
            #pragma unroll
            for (int nt = 0; nt < 4; ++nt) { float vv = acc[m][nt][r]; s += vv * vv; }
            s += __shfl_xor(s, 1);
            s += __shfl_xor(s, 2);
            s += __shfl_xor(s, 4);
            s += __shfl_xor(s, 8);
            if (ln == 0) wpart[w][m * 16 + g * 4 + r] = s;
        }
    }

    // x.b: reduce the 4 threads sharing a row (lane bits 0..1)
    {
        float s = bacc;
        s += __shfl_xor(s, 1);
        s += __shfl_xor(s, 2);
        if ((lane & 3) == 0) bpart[t >> 2] = s;
    }
    __syncthreads();

    if (t < BM) {
        float y = c[0] + bpart[t];
        #pragma unroll
        for (int ww = 0; ww < 8; ++ww) y += wpart[ww][t];
        out[(size_t)blockIdx.x * BM + t] = y;
    }
}

extern "C" void kernel_launch(void* const* d_in, const int* in_sizes, int n_in,
                              void* d_out, int out_size, void* d_ws, size_t ws_size,
                              hipStream_t stream) {
    const float* x = (const float*)d_in[0];
    const float* L = (const float*)d_in[1];
    const float* b = (const float*)d_in[2];
    const float* c = (const float*)d_in[3];
    float* out = (float*)d_out;
    unsigned short* Ltf = (unsigned short*)d_ws;   // 512 KiB

    prep_lt<<<256, 256, 0, stream>>>(L, Ltf);
    psd_main<<<NBLOCKS, THREADS, 0, stream>>>(x, Ltf, b, c, out);
}

// Round 13
// 124.136 us; speedup vs baseline: 1.0011x; 1.0011x over previous
//
#include <hip/hip_runtime.h>
#include <stdint.h>

#define D_DIM   512
#define BM      64
#define THREADS 256            // 4 waves; each wave owns 128 N-cols (nt=8)
#define NBLOCKS 2048           // 131072 / 64

typedef __attribute__((ext_vector_type(8))) __bf16 bf16x8;
typedef __attribute__((ext_vector_type(4))) float  f32x4;

__device__ __forceinline__ unsigned short f32_to_bf16_rne(float f) {
    uint32_t u = __builtin_bit_cast(uint32_t, f);
    u += 0x7FFFu + ((u >> 16) & 1u);
    return (unsigned short)(u >> 16);
}

// Repack L (fp32 row-major [K=512][N=512]) into bf16 fragment order:
// flat ushort idx = ((ks*32 + ntg)*64 + lane)*8 + e  holds L[k][n],
//   n = ntg*16 + (lane&15),  k = ks*32 + (lane>>4)*8 + e.
__global__ void prep_lt(const float* __restrict__ L, unsigned short* __restrict__ Ltf) {
    int o = blockIdx.x * 256 + threadIdx.x;
    #pragma unroll
    for (int i = 0; i < 4; ++i) {
        int idx  = o + i * 65536;
        int e    = idx & 7;
        int l    = (idx >> 3) & 63;
        int tile = idx >> 9;
        int ntg  = tile & 31;
        int ks   = tile >> 5;
        int n    = ntg * 16 + (l & 15);
        int k    = ks * 32 + (l >> 4) * 8 + e;
        Ltf[idx] = f32_to_bf16_rne(L[k * 512 + n]);
    }
}

__global__ __launch_bounds__(THREADS, 2)
void psd_main(const float* __restrict__ x, const unsigned short* __restrict__ Ltf,
              const float* __restrict__ b, const float* __restrict__ c,
              float* __restrict__ out) {
    // fp32 staging pad: 3 slots of [64 rows][32 cols] (8 KiB each), stored
    // 16B-unit u at row r holds logical unit u^(r&7) (involution).
    __shared__ __align__(16) float pad[3][BM * 32];
    // bf16 operand ring: 2 slots of [64 rows][32 cols] (4 KiB each), stored
    // 16B-unit u at row r holds logical unit u^(r&3).
    __shared__ __align__(16) unsigned short ringb[2][BM * 32];
    __shared__ __align__(16) float bsh[D_DIM];
    __shared__ float wpart[4][BM];
    __shared__ float bpart[BM];

    const int t    = threadIdx.x;
    const int w    = t >> 6;
    const int lane = t & 63;
    const int g    = lane >> 4;
    const int ln   = lane & 15;
    const int r8   = lane >> 3;       // stage: row sub-index
    const int u8   = lane & 7;        // stage: stored 16B unit
    const int crow = t >> 2;          // cvt/XB: row 0..63
    const int ccg  = t & 3;           // cvt/XB: col-group (8 fp32)

    char* padB = (char*)&pad[0][0];
    char* rngB = (char*)&ringb[0][0];
    char* bshB = (char*)&bsh[0];
    const char* xB = (const char*)x + (size_t)blockIdx.x * (BM * 2048);
    const unsigned short* LtW = Ltf + (size_t)w * 4096 + (size_t)lane * 8;

    f32x4 acc[4][8];
    #pragma unroll
    for (int m = 0; m < 4; ++m)
        #pragma unroll
        for (int nt = 0; nt < 8; ++nt)
            acc[m][nt] = (f32x4){0.f, 0.f, 0.f, 0.f};
    float bacc = 0.f;

    // Stage fp32 slice K (cols [K*32,K*32+32)) into pad slot SOFF (byte offset).
#define STAGE(K, SOFF)                                                                   \
    {                                                                                    \
        char* ldsw = padB + (SOFF) + w * 2048;                                           \
        _Pragma("unroll")                                                                \
        for (int j = 0; j < 2; ++j) {                                                    \
            const int row = w * 16 + j * 8 + r8;                                         \
            const char* gsrc = xB + (size_t)row * 2048 + (K) * 128 + ((u8 ^ r8) << 4);   \
            __builtin_amdgcn_global_load_lds(                                            \
                (const __attribute__((address_space(1))) void*)gsrc,                     \
                (__attribute__((address_space(3))) void*)(ldsw + j * 1024), 16, 0, 0);   \
        }                                                                                \
    }

    // Convert slice K (pad byte-offset COFF) -> bf16 ring slot ROFF; fuse x.b.
#define CVT_XB(K, COFF, ROFF)                                                            \
    {                                                                                    \
        const char* ps = padB + (COFF);                                                  \
        f32x4 e0 = *(const f32x4*)(ps + crow * 128 + (((ccg * 2    ) ^ (crow & 7)) << 4)); \
        f32x4 e1 = *(const f32x4*)(ps + crow * 128 + (((ccg * 2 + 1) ^ (crow & 7)) << 4)); \
        f32x4 b0 = *(const f32x4*)(bshB + (K) * 128 + ccg * 32);                         \
        f32x4 b1 = *(const f32x4*)(bshB + (K) * 128 + ccg * 32 + 16);                    \
        bacc += e0[0]*b0[0] + e0[1]*b0[1] + e0[2]*b0[2] + e0[3]*b0[3]                    \
              + e1[0]*b1[0] + e1[1]*b1[1] + e1[2]*b1[2] + e1[3]*b1[3];                   \
        bf16x8 hv;                                                                       \
        hv[0]=(__bf16)e0[0]; hv[1]=(__bf16)e0[1]; hv[2]=(__bf16)e0[2]; hv[3]=(__bf16)e0[3]; \
        hv[4]=(__bf16)e1[0]; hv[5]=(__bf16)e1[1]; hv[6]=(__bf16)e1[2]; hv[7]=(__bf16)e1[3]; \
        *(bf16x8*)(rngB + (ROFF) + crow * 64 + ((ccg ^ (crow & 3)) << 4)) = hv;          \
    }

    // Load 4 B-fragments (half H of step Q) into DST.
#define LOADB(DST, Q, H)                                                                 \
    {                                                                                    \
        _Pragma("unroll")                                                                \
        for (int i = 0; i < 4; ++i)                                                      \
            (DST)[i] = *(const bf16x8*)(LtW + (size_t)(Q) * 16384 + ((H) * 4 + i) * 512); \
    }

    // 16 MFMAs: ring slot ROFF, B-set BS, acc columns [NB, NB+4)
#define COMPUTE_H(ROFF, BS, NB)                                                          \
    {                                                                                    \
        _Pragma("unroll")                                                                \
        for (int m = 0; m < 4; ++m) {                                                    \
            const int row = m * 16 + ln;                                                 \
            bf16x8 a = *(const bf16x8*)(rngB + (ROFF) + row * 64 + ((g ^ (row & 3)) << 4)); \
            _Pragma("unroll")                                                            \
            for (int nt = 0; nt < 4; ++nt)                                               \
                acc[m][(NB) + nt] = __builtin_amdgcn_mfma_f32_16x16x32_bf16(a, (BS)[nt], acc[m][(NB) + nt], 0, 0, 0); \
        }                                                                                \
    }

    // ---- prologue: b + slices 0..2; first cvt; first B-sets ----
    if (lane < 32) {
        const char* gsrc = (const char*)b + (size_t)(w * 512 + lane * 16);
        __builtin_amdgcn_global_load_lds(
            (const __attribute__((address_space(1))) void*)gsrc,
            (__attribute__((address_space(3))) void*)(bshB + w * 512 + lane * 16), 16, 0, 0);
    }
    STAGE(0, 0)
    STAGE(1, 8192)
    STAGE(2, 16384)
    asm volatile("s_waitcnt vmcnt(4)" ::: "memory");   // b + slice0 landed; 1,2 flying
    __builtin_amdgcn_s_barrier();

    bf16x8 blo0[4], blo1[4], bhi0[4], bhi1[4];
    LOADB(blo0, 0, 0)
    LOADB(blo1, 1, 0)
    LOADB(bhi0, 0, 1)
    CVT_XB(0, 0, 0)
    asm volatile("s_waitcnt lgkmcnt(0)" ::: "memory");
    __builtin_amdgcn_s_barrier();                      // ring slot 0 ready

    // ---- hot loop: q = 0..11 (6 pairs), fully uniform ----
    int soff = 0;        // stage slot byte-offset for S(q+3): (q%3)*8192
    int coff = 8192;     // cvt slot byte-offset for slice q+1: ((q+1)%3)*8192
    int sK   = 3;        // stage slice index
    int cK   = 1;        // cvt slice index
    const unsigned short* Lp = LtW;

    #pragma unroll 1
    for (int qp = 0; qp < 6; ++qp) {
        // ---- even substep: consume blo0/bhi0, ring slot 0 ----
        LOADB(bhi1, (Lp - LtW) / 8192 + 1, 1)          // B-hi(q+1)
        STAGE(sK, soff)
        COMPUTE_H(0, blo0, 0)
        LOADB(blo0, (Lp - LtW) / 8192 + 2, 0)          // B-lo(q+2), regs just died
        COMPUTE_H(0, bhi0, 4)
        asm volatile("s_waitcnt vmcnt(10)" ::: "memory");
        CVT_XB(cK, coff, 4096)
        asm volatile("s_waitcnt lgkmcnt(0)" ::: "memory");
        __builtin_amdgcn_s_barrier();
        soff = (soff == 16384) ? 0 : soff + 8192;
        coff = (coff == 16384) ? 0 : coff + 8192;
        ++sK; ++cK; Lp += 8192;

        // ---- odd substep: consume blo1/bhi1, ring slot 1 ----
        LOADB(bhi0, (Lp - LtW) / 8192 + 1, 1)
        STAGE(sK, soff)
        COMPUTE_H(4096, blo1, 0)
        LOADB(blo1, (Lp - LtW) / 8192 + 2, 0)
        COMPUTE_H(4096, bhi1, 4)
        asm volatile("s_waitcnt vmcnt(10)" ::: "memory");
        CVT_XB(cK, coff, 0)
        asm volatile("s_waitcnt lgkmcnt(0)" ::: "memory");
        __builtin_amdgcn_s_barrier();
        soff = (soff == 16384) ? 0 : soff + 8192;
        coff = (coff == 16384) ? 0 : coff + 8192;
        ++sK; ++cK; Lp += 8192;
    }

    // ---- peeled steps q=12..15 (static offsets) ----
    // q=12 (even, ring0): stage S15, bhi(13), blo(14), cvt(13)
    LOADB(bhi1, 13, 1)
    STAGE(15, 0)                    // 15%3 = 0
    COMPUTE_H(0, blo0, 0)
    LOADB(blo0, 14, 0)
    COMPUTE_H(0, bhi0, 4)
    asm volatile("s_waitcnt vmcnt(10)" ::: "memory");
    CVT_XB(13, 8192, 4096)          // 13%3 = 1
    asm volatile("s_waitcnt lgkmcnt(0)" ::: "memory");
    __builtin_amdgcn_s_barrier();

    // q=13 (odd, ring1): no stage; bhi(14), blo(15), cvt(14)
    LOADB(bhi0, 14, 1)
    COMPUTE_H(4096, blo1, 0)
    LOADB(blo1, 15, 0)
    COMPUTE_H(4096, bhi1, 4)
    asm volatile("s_waitcnt vmcnt(8)" ::: "memory");
    CVT_XB(14, 16384, 0)            // 14%3 = 2
    asm volatile("s_waitcnt lgkmcnt(0)" ::: "memory");
    __builtin_amdgcn_s_barrier();

    // q=14 (even, ring0): bhi(15); cvt(15)
    LOADB(bhi1, 15, 1)
    COMPUTE_H(0, blo0, 0)
    COMPUTE_H(0, bhi0, 4)
    asm volatile("s_waitcnt vmcnt(4)" ::: "memory");
    CVT_XB(15, 0, 4096)             // 15%3 = 0
    asm volatile("s_waitcnt lgkmcnt(0)" ::: "memory");
    __builtin_amdgcn_s_barrier();

    // q=15 (odd, ring1): compute only
    COMPUTE_H(4096, blo1, 0)
    COMPUTE_H(4096, bhi1, 4)

#undef STAGE
#undef CVT_XB
#undef LOADB
#undef COMPUTE_H

    // rowsum of squares; C/D layout: col = lane&15, row = 4*(lane>>4) + reg
    #pragma unroll
    for (int m = 0; m < 4; ++m) {
        #pragma unroll
        for (int r = 0; r < 4; ++r) {
            float s = 0.f;
            #pragma unroll
            for (int nt = 0; nt < 8; ++nt) { float vv = acc[m][nt][r]; s += vv * vv; }
            s += __shfl_xor(s, 1);
            s += __shfl_xor(s, 2);
            s += __shfl_xor(s, 4);
            s += __shfl_xor(s, 8);
            if (ln == 0) wpart[w][m * 16 + g * 4 + r] = s;
        }
    }

    // x.b: reduce the 4 threads sharing a row
    {
        float s = bacc;
        s += __shfl_xor(s, 1);
        s += __shfl_xor(s, 2);
        if ((lane & 3) == 0) bpart[crow] = s;
    }
    __syncthreads();

    if (t < BM) {
        float y = c[0] + bpart[t]
                + wpart[0][t] + wpart[1][t] + wpart[2][t] + wpart[3][t];
        out[(size_t)blockIdx.x * BM + t] = y;
    }
}

extern "C" void kernel_launch(void* const* d_in, const int* in_sizes, int n_in,
                              void* d_out, int out_size, void* d_ws, size_t ws_size,
                              hipStream_t stream) {
    const float* x = (const float*)d_in[0];
    const float* L = (const float*)d_in[1];
    const float* b = (const float*)d_in[2];
    const float* c = (const float*)d_in[3];
    float* out = (float*)d_out;
    unsigned short* Ltf = (unsigned short*)d_ws;   // 512 KiB

    prep_lt<<<256, 256, 0, stream>>>(L, Ltf);
    psd_main<<<NBLOCKS, THREADS, 0, stream>>>(x, Ltf, b, c, out);
}